// Round 1
// baseline (141064.124 us; speedup 1.0000x reference)
//
#include <hip/hip_runtime.h>
#include <cmath>

// LIF_complex: T=8192 sequential steps over N=2048 neurons.
// Persistent cooperative kernel: 256 blocks x 256 threads, 1 block/CU.
// Each block owns 8 rows of w, kept entirely in VGPRs (64 floats/thread).
// Per step: g broadcast (global, agent-scope atomics, double-buffered in ws),
// dot products, neuron update by 8 row-leader lanes, grid barrier via
// per-step counters in ws.

#define T_STEPS 8192
#define NN      2048
#define NBLK    256
#define NTHR    256
#define ROWS_PER_BLK 8   // NN / NBLK
#define COLS_PER_THR 64  // NN / 32 lanes-per-row

__device__ __forceinline__ float stable_sigmoid(float x) {
    // matches jax.nn.sigmoid / numpy 1/(1+exp(-x)) within ~1 ulp
    if (x >= 0.0f) {
        return 1.0f / (1.0f + expf(-x));
    } else {
        float e = expf(x);
        return e / (1.0f + e);
    }
}

__global__ __launch_bounds__(NTHR, 1) void lif_kernel(
    const float* __restrict__ x_in,    // [T, N]
    const float* __restrict__ w,       // [N, N]
    const float* __restrict__ v_rest,  // [N]
    const float* __restrict__ tau_m,   // [N]
    const float* __restrict__ tau_g,   // [N]
    const float* __restrict__ pre_cp,  // [1]
    const float* __restrict__ post_cp, // [1]
    const float* __restrict__ v0,      // [N]
    const float* __restrict__ g0,      // [N]
    float* __restrict__ out,           // [2, T, N]
    float* __restrict__ gbuf,          // [2, N] double buffer (ws)
    unsigned int* __restrict__ cnt)    // [T] per-step arrival counters (ws)
{
    const int tid = threadIdx.x;
    const int b   = blockIdx.x;
    const int r   = tid >> 5;   // row within block (0..7)
    const int c   = tid & 31;   // lane within row (0..31)
    const int n   = b * ROWS_PER_BLK + r;  // global neuron/row index
    const bool leader = (c == 0);

    __shared__ float gs[NN];

    // ---- prologue: w rows into registers (one-time, 16 MB total chip-wide)
    float wreg[COLS_PER_THR];
    const float* wrow = w + (size_t)n * NN;
#pragma unroll
    for (int i = 0; i < COLS_PER_THR; ++i)
        wreg[i] = wrow[c + 32 * i];

    const float pre_c  = pre_cp[0];
    const float post_c = post_cp[0];

    float vr = 0.0f, tm = 1.0f, tg = 1.0f, v = 0.0f, g = 0.0f;
    if (leader) {
        vr = v_rest[n];
        tm = tau_m[n];
        tg = tau_g[n];
        v  = v0[n];
        g  = g0[n];
    }

    for (int t = 0; t < T_STEPS; ++t) {
        // ---- stage g(t-1) into LDS. Agent-scope relaxed atomic loads bypass
        // the (non-coherent, possibly stale) L1/L2 for the cross-XCD buffer.
        const float* gsrc = (t == 0) ? g0 : (gbuf + (size_t)(t & 1) * NN);
#pragma unroll
        for (int j = 0; j < NN / NTHR; ++j) {
            int idx = tid + NTHR * j;
            gs[idx] = __hip_atomic_load(gsrc + idx, __ATOMIC_RELAXED,
                                        __HIP_MEMORY_SCOPE_AGENT);
        }
        __syncthreads();

        float x = 0.0f;
        if (leader) x = x_in[(size_t)t * NN + n];

        // ---- dot product: row n, 64 cols/thread, strided 32
        float p = 0.0f;
#pragma unroll
        for (int i = 0; i < COLS_PER_THR; ++i)
            p = fmaf(wreg[i], gs[c + 32 * i], p);

        // ---- reduce across the 32 lanes of this row (stays within wave half)
#pragma unroll
        for (int m = 16; m >= 1; m >>= 1)
            p += __shfl_xor(p, m, 64);

        if (leader) {
            float dot = p + x;
            float I = post_c * stable_sigmoid(pre_c * dot);
            g = g - g / tg;                 // conductance decay
            v = v + (vr - v + I) / tm;      // membrane update
            float soft = stable_sigmoid(v - 30.0f);
            bool  spk  = (v >= 30.0f);
            float vnew = spk ? vr : v;
            float gnew = spk ? 1.0f : g;
            v = vnew;
            g = gnew;
            out[(size_t)t * NN + n] = vnew;
            out[(size_t)T_STEPS * NN + (size_t)t * NN + n] = soft;
            __hip_atomic_store(gbuf + (size_t)((t + 1) & 1) * NN + n, g,
                               __ATOMIC_RELAXED, __HIP_MEMORY_SCOPE_AGENT);
        }

        // ---- grid barrier: fresh counter per step (zeroed by memset)
        __syncthreads();  // all lanes done reading gs / publishing
        if (tid == 0) {
            __hip_atomic_fetch_add(cnt + t, 1u, __ATOMIC_ACQ_REL,
                                   __HIP_MEMORY_SCOPE_AGENT);
            while (__hip_atomic_load(cnt + t, __ATOMIC_ACQUIRE,
                                     __HIP_MEMORY_SCOPE_AGENT) < NBLK) {}
        }
        __syncthreads();
    }
}

extern "C" void kernel_launch(void* const* d_in, const int* in_sizes, int n_in,
                              void* d_out, int out_size, void* d_ws, size_t ws_size,
                              hipStream_t stream) {
    const float* x_in   = (const float*)d_in[0];
    const float* w      = (const float*)d_in[1];
    const float* v_rest = (const float*)d_in[2];
    const float* tau_m  = (const float*)d_in[3];
    const float* tau_g  = (const float*)d_in[4];
    const float* pre_c  = (const float*)d_in[5];
    const float* post_c = (const float*)d_in[6];
    const float* v0     = (const float*)d_in[7];
    const float* g0     = (const float*)d_in[8];
    float* out = (float*)d_out;

    // workspace layout: gbuf [2*N floats], then cnt [T u32]
    float* gbuf = (float*)d_ws;
    unsigned int* cnt = (unsigned int*)((char*)d_ws + 2 * NN * sizeof(float));

    // counters must start at 0 (ws is poisoned 0xAA before every launch)
    hipMemsetAsync(cnt, 0, T_STEPS * sizeof(unsigned int), stream);

    void* args[] = {
        (void*)&x_in, (void*)&w, (void*)&v_rest, (void*)&tau_m, (void*)&tau_g,
        (void*)&pre_c, (void*)&post_c, (void*)&v0, (void*)&g0,
        (void*)&out, (void*)&gbuf, (void*)&cnt
    };
    hipLaunchCooperativeKernel((void*)lif_kernel, dim3(NBLK), dim3(NTHR),
                               args, 0, stream);
}

// Round 2
// 38509.042 us; speedup vs baseline: 3.6631x; 3.6631x over previous
//
#include <hip/hip_runtime.h>
#include <cmath>

// LIF_complex: T=8192 sequential steps, N=2048 neurons, full coupling.
// Persistent cooperative kernel, 256 blocks x 256 threads (1 block/CU).
// Round 2: (a) dataflow sync — no grid barrier. Each neuron's g is published
// as a 64-bit {tag,t | g bits} atom; consumers spin on relaxed 8B atomic
// loads of 2048 distinct slots and proceed when tags match. Double-buffered
// by step parity (safe: writer of step t+1 observed all tags t, which
// certifies all blocks passed their post-staging __syncthreads for t-1).
// (b) w pinned in VGPRs via atomic loads (non-rematerializable) — round 1's
// VGPR_Count=56 proved the compiler was re-loading 16 MB of w from L2 every
// step. (c) x_in load issued before the spin to hide its latency.

#define T_STEPS 8192
#define NN      2048
#define NBLK    256
#define NTHR    256
#define RPB     8    // rows (neurons) per block
#define CPT     64   // w columns per thread (32 lanes cover a row)

typedef unsigned long long u64;

__device__ __forceinline__ float stable_sigmoid(float x) {
    if (x >= 0.0f) {
        return 1.0f / (1.0f + expf(-x));
    } else {
        float e = expf(x);
        return e / (1.0f + e);
    }
}

__global__ __launch_bounds__(NTHR, 1) void lif_kernel(
    const float* __restrict__ x_in,    // [T, N]
    const float* __restrict__ w,       // [N, N]
    const float* __restrict__ v_rest,  // [N]
    const float* __restrict__ tau_m,   // [N]
    const float* __restrict__ tau_g,   // [N]
    const float* __restrict__ pre_cp,  // [1]
    const float* __restrict__ post_cp, // [1]
    const float* __restrict__ v0,      // [N]
    const float* __restrict__ g0,      // [N]
    float* __restrict__ out,           // [2, T, N]
    u64* __restrict__ slots)           // [2, N] {tag|g} double buffer (ws)
{
    const int tid = threadIdx.x;
    const int b   = blockIdx.x;
    const int r   = tid >> 5;          // row within block (0..7)
    const int c   = tid & 31;          // lane within row (0..31)
    const int n   = b * RPB + r;
    const bool leader = (c == 0);

    __shared__ float gs[NN];

    // ---- w rows into VGPRs. Atomic loads cannot be rematerialized, which
    // forces the compiler to keep all 64 values register-resident for the
    // whole t-loop (round 1 re-read w from L2 every step).
    float wreg[CPT];
    const float* wrow = w + (size_t)n * NN;
#pragma unroll
    for (int i = 0; i < CPT; ++i)
        wreg[i] = __hip_atomic_load(wrow + c + 32 * i, __ATOMIC_RELAXED,
                                    __HIP_MEMORY_SCOPE_WORKGROUP);

    const float pre_c  = pre_cp[0];
    const float post_c = post_cp[0];

    float vr = 0.0f, tm = 1.0f, tg = 1.0f, v = 0.0f, g = 0.0f;
    if (leader) {
        vr = v_rest[n];
        tm = tau_m[n];
        tg = tau_g[n];
        v  = v0[n];
        g  = g0[n];
    }

    for (int t = 0; t < T_STEPS; ++t) {
        // issue the x load before the spin — latency hides behind the wait
        float x = 0.0f;
        if (leader) x = x_in[(size_t)t * NN + n];

        // ---- acquire g(t-1): dataflow spin on tagged 64-bit slots
        if (t == 0) {
#pragma unroll
            for (int j = 0; j < NN / NTHR; ++j) {
                int idx = tid + NTHR * j;
                gs[idx] = g0[idx];
            }
        } else {
            const u64* sl = slots + (size_t)((t - 1) & 1) * NN;
            const unsigned want = (unsigned)(t - 1);
#pragma unroll
            for (int j = 0; j < NN / NTHR; ++j) {
                int idx = tid + NTHR * j;
                u64 pv;
                do {
                    pv = __hip_atomic_load(sl + idx, __ATOMIC_RELAXED,
                                           __HIP_MEMORY_SCOPE_AGENT);
                } while ((unsigned)(pv >> 32) != want);
                gs[idx] = __uint_as_float((unsigned)pv);
            }
        }
        __syncthreads();

        // ---- dot product, 4-way ILP (1 wave/SIMD: ILP is the only latency hiding)
        float p0 = 0.0f, p1 = 0.0f, p2 = 0.0f, p3 = 0.0f;
#pragma unroll
        for (int i = 0; i < CPT; i += 4) {
            p0 = fmaf(wreg[i + 0], gs[c + 32 * (i + 0)], p0);
            p1 = fmaf(wreg[i + 1], gs[c + 32 * (i + 1)], p1);
            p2 = fmaf(wreg[i + 2], gs[c + 32 * (i + 2)], p2);
            p3 = fmaf(wreg[i + 3], gs[c + 32 * (i + 3)], p3);
        }
        float p = (p0 + p1) + (p2 + p3);
        // reduce across the 32 lanes of this row (xor masks stay in-row)
#pragma unroll
        for (int m = 16; m >= 1; m >>= 1)
            p += __shfl_xor(p, m, 64);

        if (leader) {
            float I = post_c * stable_sigmoid(pre_c * (p + x));
            g = g - g / tg;                 // conductance decay
            v = v + (vr - v + I) / tm;      // membrane update
            float soft = stable_sigmoid(v - 30.0f);
            bool  spk  = (v >= 30.0f);
            v = spk ? vr : v;
            g = spk ? 1.0f : g;
            out[(size_t)t * NN + n] = v;
            out[(size_t)T_STEPS * NN + (size_t)t * NN + n] = soft;
            u64 pk = ((u64)(unsigned)t << 32) | (u64)__float_as_uint(g);
            __hip_atomic_store(slots + (size_t)(t & 1) * NN + n, pk,
                               __ATOMIC_RELAXED, __HIP_MEMORY_SCOPE_AGENT);
        }

        // protect gs against next-iteration overwrite while others still read
        __syncthreads();
    }
}

extern "C" void kernel_launch(void* const* d_in, const int* in_sizes, int n_in,
                              void* d_out, int out_size, void* d_ws, size_t ws_size,
                              hipStream_t stream) {
    const float* x_in   = (const float*)d_in[0];
    const float* w      = (const float*)d_in[1];
    const float* v_rest = (const float*)d_in[2];
    const float* tau_m  = (const float*)d_in[3];
    const float* tau_g  = (const float*)d_in[4];
    const float* pre_c  = (const float*)d_in[5];
    const float* post_c = (const float*)d_in[6];
    const float* v0     = (const float*)d_in[7];
    const float* g0     = (const float*)d_in[8];
    float* out = (float*)d_out;

    u64* slots = (u64*)d_ws;  // [2, NN] tagged g slots

    // tags must not collide with any t in [0, 8192): 0xFFFFFFFF is safe
    hipMemsetAsync(slots, 0xFF, 2 * NN * sizeof(u64), stream);

    void* args[] = {
        (void*)&x_in, (void*)&w, (void*)&v_rest, (void*)&tau_m, (void*)&tau_g,
        (void*)&pre_c, (void*)&post_c, (void*)&v0, (void*)&g0,
        (void*)&out, (void*)&slots
    };
    hipLaunchCooperativeKernel((void*)lif_kernel, dim3(NBLK), dim3(NTHR),
                               args, 0, stream);
}

// Round 3
// 29334.161 us; speedup vs baseline: 4.8089x; 1.3128x over previous
//
#include <hip/hip_runtime.h>
#include <cmath>

// LIF_complex: T=8192 sequential steps, N=2048 neurons, full coupling.
// Round 3: 128 blocks x 1024 threads (16 rows/block, 1 wave per row).
//  - polls: 2 slots/thread, both issued in parallel (round 2 had 8 serialized
//    dependent spin loops per thread = ~8 L3 round trips per step).
//  - w pinned in VGPRs via asm "+v" (round 1/2 VGPR_Count 56/60 proved the
//    compiler kept rematerializing / scratch-spilling the w row chunk).
//  - outputs buffered in LDS, dumped every 64 steps (keeps scattered HBM
//    stores out of the per-step vmcnt(0) drain in the poll loop).
// Dataflow sync: 64-bit {tag=t | g bits} slots, double-buffered by parity.
// Safety: a block publishes step t+1 (overwriting parity (t-1)&1) only after
// observing all tags == t, which certifies every block passed its
// post-staging __syncthreads for step t, i.e. finished reading parity
// (t-1)&1. No barrier, no deadlock.

#define T_STEPS 8192
#define NN      2048
#define NBLK    128
#define NTHR    1024
#define RPB     16    // rows (neurons) per block
#define CPT     32    // w columns per thread (64 lanes cover a row)
#define DUMP    64    // steps buffered in LDS before an output dump

typedef unsigned long long u64;

__device__ __forceinline__ float stable_sigmoid(float x) {
    if (x >= 0.0f) {
        return 1.0f / (1.0f + expf(-x));
    } else {
        float e = expf(x);
        return e / (1.0f + e);
    }
}

__global__ __launch_bounds__(NTHR, 4) void lif_kernel(
    const float* __restrict__ x_in,    // [T, N]
    const float* __restrict__ w,       // [N, N]
    const float* __restrict__ v_rest,  // [N]
    const float* __restrict__ tau_m,   // [N]
    const float* __restrict__ tau_g,   // [N]
    const float* __restrict__ pre_cp,  // [1]
    const float* __restrict__ post_cp, // [1]
    const float* __restrict__ v0,      // [N]
    const float* __restrict__ g0,      // [N]
    float* __restrict__ out,           // [2, T, N]
    u64* __restrict__ slots)           // [2, N] {tag|g} double buffer (ws)
{
    const int tid = threadIdx.x;
    const int b   = blockIdx.x;
    const int r   = tid >> 6;          // row within block (0..15) == wave id
    const int c   = tid & 63;          // lane within row
    const int n   = b * RPB + r;
    const bool leader = (c == 0);

    __shared__ float gs[NN];           // g(t-1) staged per step (8 KB)
    __shared__ float vbuf[DUMP][RPB];  // buffered v outputs (4 KB)
    __shared__ float sbuf[DUMP][RPB];  // buffered soft-spike outputs (4 KB)

    // ---- w row chunk into VGPRs: lane c owns cols {4c..4c+3} + 256*i.
    // asm "+v" pins each value: asm results cannot be rematerialized, so the
    // 32 floats stay register-resident across the whole t-loop.
    float wreg[CPT];
    {
        const float4* wrow4 = (const float4*)(w + (size_t)n * NN);
#pragma unroll
        for (int i = 0; i < CPT / 4; ++i) {
            float4 t4 = wrow4[c + 64 * i];
            wreg[4 * i + 0] = t4.x;
            wreg[4 * i + 1] = t4.y;
            wreg[4 * i + 2] = t4.z;
            wreg[4 * i + 3] = t4.w;
        }
    }
#pragma unroll
    for (int i = 0; i < CPT; ++i)
        asm volatile("" : "+v"(wreg[i]));

    const float pre_c  = pre_cp[0];
    const float post_c = post_cp[0];

    float vr = 0.0f, tm = 1.0f, tg = 1.0f, v = 0.0f, g = 0.0f;
    if (leader) {
        vr = v_rest[n];
        tm = tau_m[n];
        tg = tau_g[n];
        v  = v0[n];
        g  = g0[n];
    }

    const int i0 = 2 * tid;
    const int i1 = 2 * tid + 1;

    for (int t = 0; t < T_STEPS; ++t) {
        // x load issued before the polls — latency hides behind the wait
        float x = 0.0f;
        if (leader) x = x_in[(size_t)t * NN + n];

        // ---- acquire g(t-1): 2 slots/thread, both polls in flight at once
        if (t == 0) {
            gs[i0] = g0[i0];
            gs[i1] = g0[i1];
        } else {
            const u64* sl = slots + (size_t)((t - 1) & 1) * NN;
            const unsigned want = (unsigned)(t - 1);
            u64 a  = __hip_atomic_load(sl + i0, __ATOMIC_RELAXED,
                                       __HIP_MEMORY_SCOPE_AGENT);
            u64 bb = __hip_atomic_load(sl + i1, __ATOMIC_RELAXED,
                                       __HIP_MEMORY_SCOPE_AGENT);
            while ((unsigned)(a >> 32) != want || (unsigned)(bb >> 32) != want) {
                a  = __hip_atomic_load(sl + i0, __ATOMIC_RELAXED,
                                       __HIP_MEMORY_SCOPE_AGENT);
                bb = __hip_atomic_load(sl + i1, __ATOMIC_RELAXED,
                                       __HIP_MEMORY_SCOPE_AGENT);
            }
            gs[i0] = __uint_as_float((unsigned)a);
            gs[i1] = __uint_as_float((unsigned)bb);
        }
        __syncthreads();

        // ---- dot product: float4 LDS reads, 4-way accumulator ILP
        float p0 = 0.0f, p1 = 0.0f, p2 = 0.0f, p3 = 0.0f;
        const float4* gs4 = (const float4*)gs;
#pragma unroll
        for (int i = 0; i < CPT / 4; ++i) {
            float4 gv = gs4[c + 64 * i];
            p0 = fmaf(wreg[4 * i + 0], gv.x, p0);
            p1 = fmaf(wreg[4 * i + 1], gv.y, p1);
            p2 = fmaf(wreg[4 * i + 2], gv.z, p2);
            p3 = fmaf(wreg[4 * i + 3], gv.w, p3);
        }
        float p = (p0 + p1) + (p2 + p3);
        // full-wave butterfly reduction (row == wave)
#pragma unroll
        for (int m = 32; m >= 1; m >>= 1)
            p += __shfl_xor(p, m, 64);

        if (leader) {
            float I = post_c * stable_sigmoid(pre_c * (p + x));
            g = g - g / tg;                 // conductance decay
            v = v + (vr - v + I) / tm;      // membrane update
            float soft = stable_sigmoid(v - 30.0f);
            bool  spk  = (v >= 30.0f);
            v = spk ? vr : v;
            g = spk ? 1.0f : g;
            vbuf[t & (DUMP - 1)][r] = v;
            sbuf[t & (DUMP - 1)][r] = soft;
            u64 pk = ((u64)(unsigned)t << 32) | (u64)__float_as_uint(g);
            __hip_atomic_store(slots + (size_t)(t & 1) * NN + n, pk,
                               __ATOMIC_RELAXED, __HIP_MEMORY_SCOPE_AGENT);
        }

        // protect gs (and order vbuf/sbuf writes) before the next iteration
        __syncthreads();

        // ---- coalesced output dump every DUMP steps.
        // Race-safe: next write to vbuf[(t+1)&63][r] happens after step
        // t+1's post-staging __syncthreads, which orders it after these reads.
        if ((t & (DUMP - 1)) == (DUMP - 1)) {
            const int t0 = t - (DUMP - 1);
            const int s  = tid >> 4;     // 0..63  (step within the window)
            const int rr = tid & 15;     // 0..15  (neuron within block)
            out[(size_t)(t0 + s) * NN + b * RPB + rr] = vbuf[s][rr];
            out[(size_t)T_STEPS * NN + (size_t)(t0 + s) * NN + b * RPB + rr]
                = sbuf[s][rr];
        }
    }
}

extern "C" void kernel_launch(void* const* d_in, const int* in_sizes, int n_in,
                              void* d_out, int out_size, void* d_ws, size_t ws_size,
                              hipStream_t stream) {
    const float* x_in   = (const float*)d_in[0];
    const float* w      = (const float*)d_in[1];
    const float* v_rest = (const float*)d_in[2];
    const float* tau_m  = (const float*)d_in[3];
    const float* tau_g  = (const float*)d_in[4];
    const float* pre_c  = (const float*)d_in[5];
    const float* post_c = (const float*)d_in[6];
    const float* v0     = (const float*)d_in[7];
    const float* g0     = (const float*)d_in[8];
    float* out = (float*)d_out;

    u64* slots = (u64*)d_ws;  // [2, NN] tagged g slots

    // tags must not collide with any t in [0, 8192): 0xFFFFFFFF is safe
    // (harness's 0xAA poison is also safe; memset is belt-and-braces)
    hipMemsetAsync(slots, 0xFF, 2 * NN * sizeof(u64), stream);

    void* args[] = {
        (void*)&x_in, (void*)&w, (void*)&v_rest, (void*)&tau_m, (void*)&tau_g,
        (void*)&pre_c, (void*)&post_c, (void*)&v0, (void*)&g0,
        (void*)&out, (void*)&slots
    };
    hipLaunchCooperativeKernel((void*)lif_kernel, dim3(NBLK), dim3(NTHR),
                               args, 0, stream);
}